// Round 5
// baseline (90.150 us; speedup 1.0000x reference)
//
#include <hip/hip_runtime.h>
#include <hip/hip_cooperative_groups.h>

namespace cg = cooperative_groups;

#define N_NODES 8192
#define N_EDGES 16384
#define IN_CH 32
#define HID 64
#define OUT_CH 2
#define EDGE_DIM 4
#define N_LAYERS 3
#define N_GRAPHS 256
#define BN_EPS 1e-5f

// ---- cooperative mega-kernel config: 256 blocks (1/CU) x 512 threads ----
#define NBLK 256
#define NT 512
#define NPB 32     // nodes per block (NBLK*NPB == N_NODES)
#define CAP 24     // in-degree bucket cap (Poisson(2): P(deg>24) ~ 1e-15)

// ---- fallback (R2, proven) config ----
#define FB_NT 512
#define FB_NPB 32

struct KP {
    const float* x; const int* edge_index; const float* edge_attr; const int* batch;
    const float* lin_in_W; const float* lin_in_b; const float* edge_W; const float* edge_b;
    const float* root_W; const float* conv_b; const float* bn_gamma; const float* bn_beta;
    const float* bn_mean; const float* bn_var; const float* clf_W; const float* clf_b;
    float* out;
    float* y4A; float* ybA; float* y4B; float* ybB; float* pooled;
};

// y for 4 nodes of wave g: y4[n][c] = (h[n]@W0..W3)[c] float4, yb[n][c] = (h[n]@B)[c].
// Weights from global (same 80 KB all blocks -> L1/L2-hot); h rows wave-private in LDS.
__device__ __forceinline__ void ynet_phase(const float* __restrict__ hs,
                                           const float* __restrict__ eW,  // [4,4096]
                                           const float* __restrict__ eB,  // [4096]
                                           float4* __restrict__ y4,
                                           float* __restrict__ yb,
                                           int node0, int c, int g) {
    float acc[4][5];
#pragma unroll
    for (int j = 0; j < 4; ++j)
#pragma unroll
        for (int d = 0; d < 5; ++d) acc[j][d] = 0.f;

    const float4* h0v = (const float4*)(hs + (g * 4 + 0) * HID);
    const float4* h1v = (const float4*)(hs + (g * 4 + 1) * HID);
    const float4* h2v = (const float4*)(hs + (g * 4 + 2) * HID);
    const float4* h3v = (const float4*)(hs + (g * 4 + 3) * HID);

#pragma unroll 2
    for (int k4 = 0; k4 < HID / 4; ++k4) {
        float4 hv[4];
        hv[0] = h0v[k4]; hv[1] = h1v[k4]; hv[2] = h2v[k4]; hv[3] = h3v[k4];
        const float* hf = (const float*)hv;
#pragma unroll
        for (int kk = 0; kk < 4; ++kk) {
            int k = k4 * 4 + kk;
            float w0 = eW[0 * 4096 + k * 64 + c];
            float w1 = eW[1 * 4096 + k * 64 + c];
            float w2 = eW[2 * 4096 + k * 64 + c];
            float w3 = eW[3 * 4096 + k * 64 + c];
            float w4 = eB[k * 64 + c];
#pragma unroll
            for (int j = 0; j < 4; ++j) {
                float hk = hf[j * 4 + kk];
                acc[j][0] += hk * w0;
                acc[j][1] += hk * w1;
                acc[j][2] += hk * w2;
                acc[j][3] += hk * w3;
                acc[j][4] += hk * w4;
            }
        }
    }
#pragma unroll
    for (int j = 0; j < 4; ++j) {
        size_t n = node0 + g * 4 + j;
        y4[n * HID + c] = make_float4(acc[j][0], acc[j][1], acc[j][2], acc[j][3]);
        yb[n * HID + c] = acc[j][4];
    }
}

// ======================= cooperative mega-kernel =======================
__global__ __launch_bounds__(NT, 2) void mega(KP P) {
    cg::grid_group grid = cg::this_grid();

    __shared__ float  hs[NPB * HID];        //  8 KB, persistent h for my 32 nodes
    __shared__ float  smem[HID * HID];      // 16 KB scratch (lin_in W+x / rootW)
    __shared__ int    cntL[NPB];
    __shared__ int    esrcL[NPB * CAP];     //  3 KB
    __shared__ float4 ea4L[NPB * CAP];      // 12 KB

    const int t = threadIdx.x;
    const int b = blockIdx.x;
    const int node0 = b * NPB;
    const int c = t & 63, g = t >> 6;       // g in 0..7, wave g owns rows 4g..4g+3

    // ---------- P0: init + edge-bucket + lin_in + ynet0 ----------
    {
        int gi = b * NT + t;
        if (gi < N_GRAPHS * HID) P.pooled[gi] = 0.f;   // blocks 0..31
    }
    if (t < NPB) cntL[t] = 0;
    float* Wis = smem;                 // 2048 floats
    float* xs  = smem + IN_CH * HID;   // 1024 floats (total 3072 <= 4096)
    for (int i = t; i < IN_CH * HID; i += NT) Wis[i] = P.lin_in_W[i];
    for (int i = t; i < NPB * IN_CH; i += NT) xs[i] = P.x[node0 * IN_CH + i];
    __syncthreads();

    // scan all edges; bucket the ones targeting my nodes into LDS
    for (int e = t; e < N_EDGES; e += NT) {
        int dst = P.edge_index[N_EDGES + e];
        int local = dst - node0;
        if ((unsigned)local < NPB) {
            int slot = atomicAdd(&cntL[local], 1);
            if (slot < CAP) {
                esrcL[local * CAP + slot] = P.edge_index[e];
                ea4L[local * CAP + slot] = *(const float4*)(P.edge_attr + 4 * (size_t)e);
            }
        }
    }

    // lin_in for my nodes (wave-private rows)
    {
        float bb = P.lin_in_b[c];
        float a0 = bb, a1 = bb, a2 = bb, a3 = bb;
        const float* x0 = xs + (g * 4 + 0) * IN_CH;
        const float* x1 = xs + (g * 4 + 1) * IN_CH;
        const float* x2 = xs + (g * 4 + 2) * IN_CH;
        const float* x3 = xs + (g * 4 + 3) * IN_CH;
#pragma unroll
        for (int k = 0; k < IN_CH; ++k) {
            float wk = Wis[k * HID + c];
            a0 += x0[k] * wk; a1 += x1[k] * wk; a2 += x2[k] * wk; a3 += x3[k] * wk;
        }
        hs[(g * 4 + 0) * HID + c] = a0;
        hs[(g * 4 + 1) * HID + c] = a1;
        hs[(g * 4 + 2) * HID + c] = a2;
        hs[(g * 4 + 3) * HID + c] = a3;
    }

    ynet_phase(hs, P.edge_W, P.edge_b, (float4*)P.y4A, P.ybA, node0, c, g);

    grid.sync();

    // ---------- layers ----------
    const float4* ycur4 = (const float4*)P.y4A;
    const float*  ycurb = P.ybA;
    float4* ynxt4 = (float4*)P.y4B;
    float*  ynxtb = P.ybB;

    for (int l = 0; l < N_LAYERS; ++l) {
        for (int i = t; i < HID * HID; i += NT)
            smem[i] = P.root_W[(size_t)l * HID * HID + i];
        __syncthreads();

        float scale = P.bn_gamma[l * HID + c] * rsqrtf(P.bn_var[l * HID + c] + BN_EPS);
        float shift = P.bn_beta[l * HID + c] - P.bn_mean[l * HID + c] * scale;
        float cb = P.conv_b[l * HID + c];

        float hnew[4];
#pragma unroll
        for (int j = 0; j < 4; ++j) {
            int ln = g * 4 + j;
            float m = 0.f;
            int d = cntL[ln]; d = (d > CAP) ? CAP : d;
            for (int s = 0; s < d; ++s) {
                int src = esrcL[ln * CAP + s];
                float4 a = ea4L[ln * CAP + s];
                float4 yv = ycur4[(size_t)src * HID + c];
                m += a.x * yv.x + a.y * yv.y + a.z * yv.z + a.w * yv.w +
                     ycurb[(size_t)src * HID + c];
            }
            float acc = 0.f;
            const float4* hv = (const float4*)(hs + ln * HID);
#pragma unroll
            for (int k4 = 0; k4 < HID / 4; ++k4) {
                float4 h4 = hv[k4];
                const float* hf = (const float*)&h4;
#pragma unroll
                for (int kk = 0; kk < 4; ++kk)
                    acc += hf[kk] * smem[(k4 * 4 + kk) * HID + c];
            }
            hnew[j] = fmaxf((m + acc + cb) * scale + shift, 0.f);
        }
#pragma unroll
        for (int j = 0; j < 4; ++j) hs[(g * 4 + j) * HID + c] = hnew[j];

        if (l < N_LAYERS - 1) {
            ynet_phase(hs, P.edge_W + (size_t)(l + 1) * EDGE_DIM * HID * HID,
                       P.edge_b + (size_t)(l + 1) * HID * HID, ynxt4, ynxtb, node0, c, g);
        } else {
#pragma unroll
            for (int j = 0; j < 4; ++j) {
                int n = node0 + g * 4 + j;
                atomicAdd(&P.pooled[P.batch[n] * HID + c], hnew[j]);
            }
        }
        const float4* t4 = ycur4; ycur4 = (const float4*)ynxt4; ynxt4 = (float4*)t4;
        const float*  tb = ycurb; ycurb = ynxtb; ynxtb = (float*)tb;

        grid.sync();
    }

    // ---------- classifier ----------
    if (b == 0 && t < N_GRAPHS) {
        float acc0 = P.clf_b[0], acc1 = P.clf_b[1];
        const float* pr = P.pooled + t * HID;
#pragma unroll
        for (int k = 0; k < HID; ++k) {
            float p = pr[k];
            acc0 += p * P.clf_W[k * 2 + 0];
            acc1 += p * P.clf_W[k * 2 + 1];
        }
        P.out[t * 2 + 0] = acc0;
        P.out[t * 2 + 1] = acc1;
    }
}

// ======================= fallback path (R2, proven @ 89.9us) =======================
__global__ __launch_bounds__(FB_NT) void fb_k0(
        const float* __restrict__ x,
        const float* __restrict__ Win, const float* __restrict__ bin,
        const float* __restrict__ eW0, const float* __restrict__ eB0,
        float* __restrict__ hA, float4* __restrict__ y4, float* __restrict__ yb,
        float* __restrict__ agg, float* __restrict__ pooled) {
    __shared__ float Wis[IN_CH * HID];
    __shared__ float xs[FB_NPB * IN_CH];
    __shared__ float hs[FB_NPB * HID];
    int t = threadIdx.x;
    int node0 = blockIdx.x * FB_NPB;

    for (int i = t; i < FB_NPB * HID; i += FB_NT) agg[node0 * HID + i] = 0.f;
    if (t < 64) pooled[blockIdx.x * 64 + t] = 0.f;   // 256 blocks x 64
    for (int i = t; i < IN_CH * HID; i += FB_NT) Wis[i] = Win[i];
    for (int i = t; i < FB_NPB * IN_CH; i += FB_NT) xs[i] = x[node0 * IN_CH + i];
    __syncthreads();

    int c = t & 63, g = t >> 6;
    float b = bin[c];
    float a0 = b, a1 = b, a2 = b, a3 = b;
    const float* x0 = xs + (g * 4 + 0) * IN_CH;
    const float* x1 = xs + (g * 4 + 1) * IN_CH;
    const float* x2 = xs + (g * 4 + 2) * IN_CH;
    const float* x3 = xs + (g * 4 + 3) * IN_CH;
#pragma unroll
    for (int k = 0; k < IN_CH; ++k) {
        float wk = Wis[k * HID + c];
        a0 += x0[k] * wk; a1 += x1[k] * wk; a2 += x2[k] * wk; a3 += x3[k] * wk;
    }
    hs[(g * 4 + 0) * HID + c] = a0; hA[(node0 + g * 4 + 0) * HID + c] = a0;
    hs[(g * 4 + 1) * HID + c] = a1; hA[(node0 + g * 4 + 1) * HID + c] = a1;
    hs[(g * 4 + 2) * HID + c] = a2; hA[(node0 + g * 4 + 2) * HID + c] = a2;
    hs[(g * 4 + 3) * HID + c] = a3; hA[(node0 + g * 4 + 3) * HID + c] = a3;
    __syncthreads();

    ynet_phase(hs, eW0, eB0, y4, yb, node0, c, g);
}

__global__ __launch_bounds__(256) void fb_edge(
        const float4* __restrict__ y4, const float* __restrict__ yb,
        const float* __restrict__ edge_attr, const int* __restrict__ edge_index,
        float* __restrict__ agg) {
    int e = blockIdx.x * 4 + (threadIdx.x >> 6);
    int lane = threadIdx.x & 63;
    int src = edge_index[e];
    int dst = edge_index[N_EDGES + e];
    float4 a = *(const float4*)(edge_attr + (size_t)e * 4);
    float4 yv = y4[(size_t)src * HID + lane];
    float m = a.x * yv.x + a.y * yv.y + a.z * yv.z + a.w * yv.w +
              yb[(size_t)src * HID + lane];
    atomicAdd(&agg[dst * HID + lane], m);
}

__global__ __launch_bounds__(FB_NT) void fb_upd(
        const float* __restrict__ h_in, float* __restrict__ agg,
        const float* __restrict__ rootW, const float* __restrict__ conv_b,
        const float* __restrict__ gam, const float* __restrict__ bet,
        const float* __restrict__ mu, const float* __restrict__ var,
        const float* __restrict__ eW_next, const float* __restrict__ eB_next,
        float* __restrict__ h_out, float4* __restrict__ y4, float* __restrict__ yb) {
    __shared__ float Ws[HID * HID];
    __shared__ float hsin[FB_NPB * HID];
    __shared__ float hs[FB_NPB * HID];
    int t = threadIdx.x;
    int node0 = blockIdx.x * FB_NPB;
    for (int i = t; i < HID * HID; i += FB_NT) Ws[i] = rootW[i];
    for (int i = t; i < FB_NPB * HID; i += FB_NT) hsin[i] = h_in[node0 * HID + i];
    __syncthreads();

    int c = t & 63, g = t >> 6;
    float scale = gam[c] * rsqrtf(var[c] + BN_EPS);
    float shift = bet[c] - mu[c] * scale;
    float cb = conv_b[c];

    float acc[4] = {0.f, 0.f, 0.f, 0.f};
    const float4* h0v = (const float4*)(hsin + (g * 4 + 0) * HID);
    const float4* h1v = (const float4*)(hsin + (g * 4 + 1) * HID);
    const float4* h2v = (const float4*)(hsin + (g * 4 + 2) * HID);
    const float4* h3v = (const float4*)(hsin + (g * 4 + 3) * HID);
#pragma unroll 4
    for (int k4 = 0; k4 < HID / 4; ++k4) {
        float4 hv[4];
        hv[0] = h0v[k4]; hv[1] = h1v[k4]; hv[2] = h2v[k4]; hv[3] = h3v[k4];
        const float* hf = (const float*)hv;
#pragma unroll
        for (int kk = 0; kk < 4; ++kk) {
            float wk = Ws[(k4 * 4 + kk) * 64 + c];
#pragma unroll
            for (int j = 0; j < 4; ++j) acc[j] += hf[j * 4 + kk] * wk;
        }
    }
#pragma unroll
    for (int j = 0; j < 4; ++j) {
        int node = node0 + g * 4 + j;
        float av = agg[node * HID + c];
        agg[node * HID + c] = 0.f;
        float v = fmaxf((av + acc[j] + cb) * scale + shift, 0.f);
        hs[(g * 4 + j) * HID + c] = v;
        h_out[node * HID + c] = v;
    }
    __syncthreads();

    ynet_phase(hs, eW_next, eB_next, y4, yb, node0, c, g);
}

__global__ __launch_bounds__(FB_NT) void fb_upd_pool(
        const float* __restrict__ h_in, float* __restrict__ agg,
        const float* __restrict__ rootW, const float* __restrict__ conv_b,
        const float* __restrict__ gam, const float* __restrict__ bet,
        const float* __restrict__ mu, const float* __restrict__ var,
        const int* __restrict__ batch, float* __restrict__ pooled) {
    __shared__ float Ws[HID * HID];
    __shared__ float hsin[FB_NPB * HID];
    int t = threadIdx.x;
    int node0 = blockIdx.x * FB_NPB;
    for (int i = t; i < HID * HID; i += FB_NT) Ws[i] = rootW[i];
    for (int i = t; i < FB_NPB * HID; i += FB_NT) hsin[i] = h_in[node0 * HID + i];
    __syncthreads();

    int c = t & 63, g = t >> 6;
    float scale = gam[c] * rsqrtf(var[c] + BN_EPS);
    float shift = bet[c] - mu[c] * scale;
    float cb = conv_b[c];

    float acc[4] = {0.f, 0.f, 0.f, 0.f};
    const float4* h0v = (const float4*)(hsin + (g * 4 + 0) * HID);
    const float4* h1v = (const float4*)(hsin + (g * 4 + 1) * HID);
    const float4* h2v = (const float4*)(hsin + (g * 4 + 2) * HID);
    const float4* h3v = (const float4*)(hsin + (g * 4 + 3) * HID);
#pragma unroll 4
    for (int k4 = 0; k4 < HID / 4; ++k4) {
        float4 hv[4];
        hv[0] = h0v[k4]; hv[1] = h1v[k4]; hv[2] = h2v[k4]; hv[3] = h3v[k4];
        const float* hf = (const float*)hv;
#pragma unroll
        for (int kk = 0; kk < 4; ++kk) {
            float wk = Ws[(k4 * 4 + kk) * 64 + c];
#pragma unroll
            for (int j = 0; j < 4; ++j) acc[j] += hf[j * 4 + kk] * wk;
        }
    }
#pragma unroll
    for (int j = 0; j < 4; ++j) {
        int node = node0 + g * 4 + j;
        float av = agg[node * HID + c];
        agg[node * HID + c] = 0.f;
        float v = fmaxf((av + acc[j] + cb) * scale + shift, 0.f);
        atomicAdd(&pooled[batch[node] * HID + c], v);
    }
}

__global__ void fb_clf(float* __restrict__ pooled,
                       const float* __restrict__ W,
                       const float* __restrict__ b,
                       float* __restrict__ out) {
    int gph = threadIdx.x;
    float acc0 = b[0], acc1 = b[1];
    float* pr = pooled + gph * HID;
#pragma unroll
    for (int k = 0; k < HID; ++k) {
        float p = pr[k];
        acc0 += p * W[k * 2 + 0];
        acc1 += p * W[k * 2 + 1];
    }
    out[gph * 2 + 0] = acc0;
    out[gph * 2 + 1] = acc1;
#pragma unroll
    for (int k = 0; k < HID; ++k) pr[k] = 0.f;
}

extern "C" void kernel_launch(void* const* d_in, const int* in_sizes, int n_in,
                              void* d_out, int out_size, void* d_ws, size_t ws_size,
                              hipStream_t stream) {
    char* ws = (char*)d_ws;
    KP p;
    p.x          = (const float*)d_in[0];
    p.edge_index = (const int*)  d_in[1];
    p.edge_attr  = (const float*)d_in[2];
    p.batch      = (const int*)  d_in[3];
    p.lin_in_W   = (const float*)d_in[4];
    p.lin_in_b   = (const float*)d_in[5];
    p.edge_W     = (const float*)d_in[6];
    p.edge_b     = (const float*)d_in[7];
    p.root_W     = (const float*)d_in[8];
    p.conv_b     = (const float*)d_in[9];
    p.bn_gamma   = (const float*)d_in[10];
    p.bn_beta    = (const float*)d_in[11];
    p.bn_mean    = (const float*)d_in[12];
    p.bn_var     = (const float*)d_in[13];
    p.clf_W      = (const float*)d_in[14];
    p.clf_b      = (const float*)d_in[15];
    p.out        = (float*)d_out;
    p.y4A   = (float*)(ws);                                 //  8 MB
    p.y4B   = (float*)(ws + (size_t) 8 * 1024 * 1024);      //  8 MB
    p.ybA   = (float*)(ws + (size_t)16 * 1024 * 1024);      //  2 MB
    p.ybB   = (float*)(ws + (size_t)18 * 1024 * 1024);      //  2 MB
    p.pooled= (float*)(ws + (size_t)20 * 1024 * 1024);      // 64 KB

    // fallback-only buffers
    float*  hA  = (float*) (ws + (size_t)21 * 1024 * 1024); // 2 MB
    float*  hB  = (float*) (ws + (size_t)23 * 1024 * 1024); // 2 MB
    float*  agg = (float*) (ws + (size_t)25 * 1024 * 1024); // 2 MB
    float*  yb  = p.ybA;
    float4* y4  = (float4*)p.y4A;
    float*  pooled = p.pooled;

    // Host-only queries (capture-safe, deterministic): gate the coop path.
    int dev = 0;
    hipGetDevice(&dev);
    int coopAttr = 0, numCU = 0, maxB = 0;
    hipDeviceGetAttribute(&coopAttr, hipDeviceAttributeCooperativeLaunch, dev);
    hipDeviceGetAttribute(&numCU, hipDeviceAttributeMultiprocessorCount, dev);
    hipError_t oe = hipOccupancyMaxActiveBlocksPerMultiprocessor(
        &maxB, (const void*)mega, NT, 0);

    hipError_t lerr = hipErrorUnknown;
    if (coopAttr && oe == hipSuccess && maxB >= 1 && maxB * numCU >= NBLK) {
        void* args[] = { &p };
        lerr = hipLaunchCooperativeKernel((const void*)mega, dim3(NBLK), dim3(NT),
                                          args, 0, stream);
    }
    if (lerr != hipSuccess) {
        // ---- fallback: proven R2 8-dispatch chain ----
        const float* edge_W = p.edge_W;
        const float* edge_b = p.edge_b;
        const float* root_W = p.root_W;
        const float* conv_b = p.conv_b;

        fb_k0<<<N_NODES / FB_NPB, FB_NT, 0, stream>>>(
            p.x, p.lin_in_W, p.lin_in_b, edge_W, edge_b, hA, y4, yb, agg, pooled);

        fb_edge<<<N_EDGES / 4, 256, 0, stream>>>(y4, yb, p.edge_attr, p.edge_index, agg);

        fb_upd<<<N_NODES / FB_NPB, FB_NT, 0, stream>>>(
            hA, agg, root_W, conv_b, p.bn_gamma, p.bn_beta, p.bn_mean, p.bn_var,
            edge_W + (size_t)1 * EDGE_DIM * HID * HID, edge_b + (size_t)1 * HID * HID,
            hB, y4, yb);

        fb_edge<<<N_EDGES / 4, 256, 0, stream>>>(y4, yb, p.edge_attr, p.edge_index, agg);

        fb_upd<<<N_NODES / FB_NPB, FB_NT, 0, stream>>>(
            hB, agg, root_W + (size_t)1 * HID * HID, conv_b + (size_t)1 * HID,
            p.bn_gamma + HID, p.bn_beta + HID, p.bn_mean + HID, p.bn_var + HID,
            edge_W + (size_t)2 * EDGE_DIM * HID * HID, edge_b + (size_t)2 * HID * HID,
            hA, y4, yb);

        fb_edge<<<N_EDGES / 4, 256, 0, stream>>>(y4, yb, p.edge_attr, p.edge_index, agg);

        fb_upd_pool<<<N_NODES / FB_NPB, FB_NT, 0, stream>>>(
            hA, agg, root_W + (size_t)2 * HID * HID, conv_b + (size_t)2 * HID,
            p.bn_gamma + 2 * HID, p.bn_beta + 2 * HID, p.bn_mean + 2 * HID,
            p.bn_var + 2 * HID, p.batch, pooled);

        fb_clf<<<1, 256, 0, stream>>>(pooled, p.clf_W, p.clf_b, p.out);
    }
}